// Round 1
// baseline (8430.402 us; speedup 1.0000x reference)
//
#include <hip/hip_runtime.h>
#include <stdint.h>

// ---------------------------------------------------------------------------
// 2-layer LSTM, B=64, T=512, E=512, H=1024, then [64,1024]@V.T+bV -> [64,10].
//
// Design:
//  - embed_kernel: gather emb[x[b,t]] -> xs[t][b][512] bf16 (in d_ws).
//  - lstm_kernel: persistent, 256 WGs x 256 thr, 1 block/CU (LDS 139264B).
//      WGs 0..127   = layer-0 (8 hidden units each, K=1536: xs part + h0)
//      WGs 128..255 = layer-1 (8 hidden units each, K=2048: h0' , h1)
//      Software pipeline: tick tau runs L0 step tau and L1 step tau-1.
//      Weights bf16, pre-packed in LDS in MFMA A-fragment order (read once
//      from HBM). mfma_f32_16x16x32_bf16; fp32 accum; c-state in registers.
//      One flag-tree grid barrier per tick (513), agent-scope fences for
//      cross-XCD h visibility. h double-buffered by step parity.
//  - cls_kernel: out = h1_final(fp32) @ V.T + bV.
// ---------------------------------------------------------------------------

typedef __attribute__((ext_vector_type(8))) short bf16x8;   // 8 bf16 in 4 VGPRs
typedef __attribute__((ext_vector_type(4))) float f32x4;

__device__ __forceinline__ unsigned short f2bf(float x) {
    unsigned u = __float_as_uint(x);
    u = (u + 0x7FFFu + ((u >> 16) & 1u)) >> 16;   // RNE
    return (unsigned short)u;
}

__device__ __forceinline__ f32x4 mfma16(bf16x8 a, bf16x8 b, f32x4 c) {
    return __builtin_amdgcn_mfma_f32_16x16x32_bf16(a, b, c, 0, 0, 0);
}

// ---------------- embedding gather + bf16 convert --------------------------
// xs[t][b][k], t<512, b<64, k<512. One thread per 8 elems.
__global__ __launch_bounds__(256) void embed_kernel(
    const int* __restrict__ x, const float* __restrict__ emb,
    unsigned short* __restrict__ xs)
{
    int e = blockIdx.x * 256 + threadIdx.x;     // 0 .. 2097151
    int t  = e >> 12;                           // / (64*64)
    int r  = e & 4095;
    int b  = r >> 6;
    int k8 = (r & 63) << 3;
    int tok = x[b * 512 + t];                   // x[b][t]
    const float* src = emb + (size_t)tok * 512 + k8;
    unsigned short* dst = xs + ((size_t)(t * 64 + b)) * 512 + k8;
#pragma unroll
    for (int i = 0; i < 8; ++i) dst[i] = f2bf(src[i]);
}

// ---------------- zero h buffers + barrier state ---------------------------
__global__ __launch_bounds__(256) void init_kernel(unsigned int* __restrict__ p, int n)
{
    int i = blockIdx.x * 256 + threadIdx.x;
    if (i < n) p[i] = 0u;
}

// ---------------- persistent LSTM kernel -----------------------------------
#define LDS_GWS_OFF 131072
#define LDS_TOTAL   139264

__global__ __launch_bounds__(256, 1) void lstm_kernel(
    const unsigned short* __restrict__ xs,
    unsigned short* __restrict__ h0buf,   // [2][64][1024] bf16
    unsigned short* __restrict__ h1buf,   // [2][64][1024] bf16
    float* __restrict__ h1f,              // [64][1024] fp32 (final h1)
    unsigned int* __restrict__ bar,       // arrive[256] @0, release @ [320]
    const float* __restrict__ W0, const float* __restrict__ b0,
    const float* __restrict__ W1, const float* __restrict__ b1)
{
    extern __shared__ char smem[];
    bf16x8* Afrag = (bf16x8*)smem;                    // [nk][2 mtiles][64 lanes]
    float*  gws   = (float*)(smem + LDS_GWS_OFF);     // 4 waves * 512 fp32

    const int wg  = blockIdx.x;
    const int tid = threadIdx.x;
    const bool isL1 = (wg >= 128);
    const int w   = isL1 ? wg - 128 : wg;   // 0..127
    const int w8  = w * 8;                  // first hidden unit owned
    const int nk  = isL1 ? 64 : 48;         // K blocks of 32
    const float* W = isL1 ? W1 : W0;
    const int wstride = isL1 ? 2048 : 1536;
    const float* bias = isL1 ? b1 : b0;

    // ---- stage weights into LDS, packed in A-fragment order ----
    // frag f = (kblk*2 + mt)*64 + lane; lane holds row m=(lane&15) of mtile,
    // k = kblk*32 + (lane>>4)*8 + j.  Local row m16 -> chunk c=m16>>2,
    // unit ul = mt*4 + (m16&3); global gate row = c*1024 + w8 + ul.
    for (int f = tid; f < nk * 128; f += 256) {
        int kblk = f >> 7;
        int r    = f & 127;
        int mt   = r >> 6;
        int lane = r & 63;
        int m16  = lane & 15;
        int q    = lane >> 4;
        int c    = m16 >> 2;
        int ul   = mt * 4 + (m16 & 3);
        int grow = c * 1024 + w8 + ul;
        const float* src = W + (size_t)grow * wstride + kblk * 32 + q * 8;
        bf16x8 v;
#pragma unroll
        for (int i = 0; i < 8; ++i) v[i] = (short)f2bf(src[i]);
        Afrag[f] = v;
    }

    const int lane = tid & 63;
    const int wv   = tid >> 6;         // wave id = batch tile
    const int n16  = lane & 15;
    const int q4   = lane >> 4;
    const int brow = wv * 16 + n16;    // batch row for K-loop B frags

    // per-thread biases for its 2 cells (mt 0/1, unit q4), 4 chunks each
    float bi[2][4];
#pragma unroll
    for (int cell = 0; cell < 2; ++cell) {
        int j = w8 + cell * 4 + q4;
#pragma unroll
        for (int c = 0; c < 4; ++c) bi[cell][c] = bias[c * 1024 + j];
    }
    float cst0 = 0.f, cst1 = 0.f;      // cell state, lives here 512 steps

    __syncthreads();

    unsigned gen = 0;
    for (int tick = 0; tick < 513; ++tick) {
        int t = isL1 ? (tick - 1) : tick;
        if (t >= 0 && t < 512) {
            const int p = t & 1;
            f32x4 acc0 = (f32x4){0.f, 0.f, 0.f, 0.f};
            f32x4 acc1 = (f32x4){0.f, 0.f, 0.f, 0.f};

            if (!isL1) {
                // K part 1: embedded input xs[t], kblk 0..15
                const unsigned short* xsp =
                    xs + ((size_t)(t * 64 + brow)) * 512 + q4 * 8;
#pragma unroll 4
                for (int kb = 0; kb < 16; ++kb) {
                    bf16x8 bf = *(const bf16x8*)(xsp + kb * 32);
                    bf16x8 a0 = Afrag[(kb * 2 + 0) * 64 + lane];
                    bf16x8 a1 = Afrag[(kb * 2 + 1) * 64 + lane];
                    acc0 = mfma16(a0, bf, acc0);
                    acc1 = mfma16(a1, bf, acc1);
                }
                // K part 2: h0(t-1), kblk 16..47
                const unsigned short* hp =
                    h0buf + (size_t)(p ^ 1) * 65536 + (size_t)brow * 1024 + q4 * 8;
#pragma unroll 4
                for (int kb = 0; kb < 32; ++kb) {
                    bf16x8 bf = *(const bf16x8*)(hp + kb * 32);
                    int kk = kb + 16;
                    bf16x8 a0 = Afrag[(kk * 2 + 0) * 64 + lane];
                    bf16x8 a1 = Afrag[(kk * 2 + 1) * 64 + lane];
                    acc0 = mfma16(a0, bf, acc0);
                    acc1 = mfma16(a1, bf, acc1);
                }
            } else {
                // K part 1: h0(t) (produced by L0 last tick), kblk 0..31
                const unsigned short* hp0 =
                    h0buf + (size_t)p * 65536 + (size_t)brow * 1024 + q4 * 8;
#pragma unroll 4
                for (int kb = 0; kb < 32; ++kb) {
                    bf16x8 bf = *(const bf16x8*)(hp0 + kb * 32);
                    bf16x8 a0 = Afrag[(kb * 2 + 0) * 64 + lane];
                    bf16x8 a1 = Afrag[(kb * 2 + 1) * 64 + lane];
                    acc0 = mfma16(a0, bf, acc0);
                    acc1 = mfma16(a1, bf, acc1);
                }
                // K part 2: h1(t-1), kblk 32..63
                const unsigned short* hp1 =
                    h1buf + (size_t)(p ^ 1) * 65536 + (size_t)brow * 1024 + q4 * 8;
#pragma unroll 4
                for (int kb = 0; kb < 32; ++kb) {
                    bf16x8 bf = *(const bf16x8*)(hp1 + kb * 32);
                    int kk = kb + 32;
                    bf16x8 a0 = Afrag[(kk * 2 + 0) * 64 + lane];
                    bf16x8 a1 = Afrag[(kk * 2 + 1) * 64 + lane];
                    acc0 = mfma16(a0, bf, acc0);
                    acc1 = mfma16(a1, bf, acc1);
                }
            }

            // scatter accumulators to per-wave LDS:  [mt][chunk][unit][n16]
            // C/D layout: col = lane&15 (=n16), row = q4*4 + reg -> chunk=q4, unit=reg
            float* g = gws + wv * 512;
#pragma unroll
            for (int r = 0; r < 4; ++r) {
                g[      q4 * 64 + r * 16 + n16] = acc0[r];
                g[256 + q4 * 64 + r * 16 + n16] = acc1[r];
            }
            // same-wave produce/consume; compiler orders via lgkmcnt

            unsigned short* hw = (isL1 ? h1buf : h0buf) + (size_t)p * 65536;
#pragma unroll
            for (int cell = 0; cell < 2; ++cell) {
                const float* gg = gws + wv * 512 + cell * 256;
                float xi = gg[0 * 64 + q4 * 16 + n16] + bi[cell][0];
                float xf = gg[1 * 64 + q4 * 16 + n16] + bi[cell][1];
                float xg = gg[2 * 64 + q4 * 16 + n16] + bi[cell][2];
                float xo = gg[3 * 64 + q4 * 16 + n16] + bi[cell][3];
                float si = 1.f / (1.f + expf(-xi));
                float sf = 1.f / (1.f + expf(-xf));
                float tg = tanhf(xg);
                float so = 1.f / (1.f + expf(-xo));
                float cprev = cell ? cst1 : cst0;
                float cn = sf * cprev + si * tg;
                if (cell) cst1 = cn; else cst0 = cn;
                float h = so * tanhf(cn);
                size_t hidx = (size_t)brow * 1024 + (size_t)(w8 + cell * 4 + q4);
                hw[hidx] = f2bf(h);
                if (isL1 && t == 511) h1f[hidx] = h;
            }
        }

        // ---- grid barrier (flag tree), one per tick ----
        gen++;
        __syncthreads();   // drains this WG's vmem stores (waitcnt before s_barrier)
        if (tid == 0) {
            __builtin_amdgcn_fence(__ATOMIC_RELEASE, "agent");   // L2 writeback
            __hip_atomic_store(&bar[wg], gen, __ATOMIC_RELAXED, __HIP_MEMORY_SCOPE_AGENT);
        }
        if (wg == 0) {
            unsigned v;
            do {
                v = __hip_atomic_load(&bar[tid], __ATOMIC_RELAXED, __HIP_MEMORY_SCOPE_AGENT);
                if (v < gen) __builtin_amdgcn_s_sleep(1);
            } while (v < gen);
            __syncthreads();           // all 256 arrive flags observed
            if (tid == 0) {
                __builtin_amdgcn_fence(__ATOMIC_ACQUIRE, "agent");  // inv caches
                __hip_atomic_store(&bar[320], gen, __ATOMIC_RELAXED, __HIP_MEMORY_SCOPE_AGENT);
            }
        } else if (tid == 0) {
            unsigned v;
            do {
                v = __hip_atomic_load(&bar[320], __ATOMIC_RELAXED, __HIP_MEMORY_SCOPE_AGENT);
                if (v < gen) __builtin_amdgcn_s_sleep(1);
            } while (v < gen);
            __builtin_amdgcn_fence(__ATOMIC_ACQUIRE, "agent");      // inv caches
        }
        __syncthreads();
    }
}

// ---------------- classifier: out = h1f @ V.T + bV -------------------------
__global__ __launch_bounds__(64) void cls_kernel(
    const float* __restrict__ h1f, const float* __restrict__ V,
    const float* __restrict__ bV, float* __restrict__ out)
{
    int b = blockIdx.x;
    int lane = threadIdx.x;
    float p[10];
#pragma unroll
    for (int c = 0; c < 10; ++c) p[c] = 0.f;
    for (int k = lane; k < 1024; k += 64) {
        float h = h1f[(size_t)b * 1024 + k];
#pragma unroll
        for (int c = 0; c < 10; ++c) p[c] += h * V[(size_t)c * 1024 + k];
    }
#pragma unroll
    for (int c = 0; c < 10; ++c) {
        float v = p[c];
#pragma unroll
        for (int off = 32; off > 0; off >>= 1) v += __shfl_down(v, off);
        if (lane == 0) out[b * 10 + c] = v + bV[c];
    }
}

// ---------------- launch ---------------------------------------------------
// ws layout (bytes):
//   [0, 33554432)          xs  bf16 [512][64][512]
//   +0        h0buf bf16 [2][64][1024]   (262144)
//   +262144   h1buf bf16 [2][64][1024]   (262144)
//   +524288   h1f   fp32 [64][1024]      (262144)
//   +786432   barrier (4096)
// total 34344960 bytes required of ws_size.
extern "C" void kernel_launch(void* const* d_in, const int* in_sizes, int n_in,
                              void* d_out, int out_size, void* d_ws, size_t ws_size,
                              hipStream_t stream)
{
    const int*   x   = (const int*)d_in[0];
    const float* emb = (const float*)d_in[1];
    const float* W0  = (const float*)d_in[2];
    const float* b0  = (const float*)d_in[3];
    const float* W1  = (const float*)d_in[4];
    const float* b1  = (const float*)d_in[5];
    const float* V   = (const float*)d_in[6];
    const float* bV  = (const float*)d_in[7];
    float* out = (float*)d_out;

    char* ws = (char*)d_ws;
    unsigned short* xs  = (unsigned short*)ws;
    char* dyn = ws + 33554432;
    unsigned short* h0  = (unsigned short*)(dyn);
    unsigned short* h1  = (unsigned short*)(dyn + 262144);
    float*          h1f = (float*)(dyn + 524288);
    unsigned int*   bar = (unsigned int*)(dyn + 786432);

    // zero h buffers + h1f + barrier state (790528 B = 197632 dwords)
    hipLaunchKernelGGL(init_kernel, dim3(772), dim3(256), 0, stream,
                       (unsigned int*)dyn, 197632);
    hipLaunchKernelGGL(embed_kernel, dim3(8192), dim3(256), 0, stream, x, emb, xs);
    hipLaunchKernelGGL(lstm_kernel, dim3(256), dim3(256), LDS_TOTAL, stream,
                       xs, h0, h1, h1f, bar, W0, b0, W1, b1);
    hipLaunchKernelGGL(cls_kernel, dim3(64), dim3(64), 0, stream, h1f, V, bV, out);
}